// Round 1
// baseline (520.559 us; speedup 1.0000x reference)
//
#include <hip/hip_runtime.h>
#include <math.h>

#define NTOK   16384
#define DDIM   2048
#define EDIM   128
#define HDIM   128
#define TOKT   64
#define KT     64

// XOR-swizzled index into a [64][128] LDS array: conflict-free for both
// row-access (fixed t, lane = e) and column-access (lane = t, fixed e).
__device__ __forceinline__ int swz(int t, int e) {
  return t * EDIM + ((e & 96) | ((e ^ t) & 31));
}

__global__ __launch_bounds__(512)
void fused_router(const float* __restrict__ x,
                  const float* __restrict__ Wr,
                  const float* __restrict__ Wd,
                  const float* __restrict__ gamma,
                  const float* __restrict__ beta,
                  const float* __restrict__ rnn,
                  const float* __restrict__ gum,
                  float* __restrict__ outb,
                  float* __restrict__ outa) {
  __shared__ union {
    float xs[TOKT][KT + 1];                              // 16.6 KB, K-loop
    struct { float a[TOKT * EDIM]; float g[TOKT * EDIM]; } ep;  // 64 KiB, epilogue
  } sm;

  const int tid  = (int)threadIdx.x;
  const int wv   = __builtin_amdgcn_readfirstlane(tid >> 6);  // wave id, uniform
  const int lane = tid & 63;
  const int t0   = (int)blockIdx.x * TOKT;
  const int e0   = wv * 16;

  float acc[16];
#pragma unroll
  for (int j = 0; j < 16; ++j) acc[j] = 0.0f;

  // ---- router GEMM: out[t,e] = sum_d x[t,d] * Wr[e,d] ----
  // register-prefetch of next x chunk; W via wave-uniform scalar loads.
  float pre[8];
#pragma unroll
  for (int i = 0; i < 8; ++i) {
    int idx = tid + i * 512;
    pre[i] = x[(size_t)(t0 + (idx >> 6)) * DDIM + (idx & (KT - 1))];
  }

  for (int k0 = 0; k0 < DDIM; k0 += KT) {
    __syncthreads();                       // previous compute done reading xs
#pragma unroll
    for (int i = 0; i < 8; ++i) {
      int idx = tid + i * 512;
      sm.xs[idx >> 6][idx & (KT - 1)] = pre[i];
    }
    if (k0 + KT < DDIM) {
#pragma unroll
      for (int i = 0; i < 8; ++i) {
        int idx = tid + i * 512;
        pre[i] = x[(size_t)(t0 + (idx >> 6)) * DDIM + (k0 + KT) + (idx & (KT - 1))];
      }
    }
    __syncthreads();
    const float* wb = Wr + (size_t)e0 * DDIM + k0;   // uniform base -> s_load
#pragma unroll 4
    for (int k = 0; k < KT; ++k) {
      const float xv = sm.xs[lane][k];               // lane = token, conflict-free
#pragma unroll
      for (int j = 0; j < 16; ++j)
        acc[j] = fmaf(xv, wb[(size_t)j * DDIM + k], acc[j]);
    }
  }
  __syncthreads();                                   // xs dead; reuse LDS as ep

  float* const A = sm.ep.a;
  float* const G = sm.ep.g;

  // ---- phase 1: out (+rnn_state) -> LDS ----
#pragma unroll
  for (int j = 0; j < 16; ++j) A[swz(lane, e0 + j)] = acc[j] + rnn[e0 + j];
  __syncthreads();

  // ---- phase 2: LayerNorm + exact GELU, one token per wave-iteration ----
  {
    const float gm0 = gamma[lane], gm1 = gamma[lane + 64];
    const float bt0 = beta[lane],  bt1 = beta[lane + 64];
    for (int tt = wv * 8; tt < wv * 8 + 8; ++tt) {
      float v0 = A[swz(tt, lane)];
      float v1 = A[swz(tt, lane + 64)];
      float s = v0 + v1;
#pragma unroll
      for (int m = 32; m; m >>= 1) s += __shfl_xor(s, m);
      const float mu = s * (1.0f / 128.0f);
      const float d0 = v0 - mu, d1 = v1 - mu;
      float q = d0 * d0 + d1 * d1;
#pragma unroll
      for (int m = 32; m; m >>= 1) q += __shfl_xor(q, m);
      const float rstd = 1.0f / sqrtf(q * (1.0f / 128.0f) + 1e-5f);
      const float h0v = d0 * rstd * gm0 + bt0;
      const float h1v = d1 * rstd * gm1 + bt1;
      G[swz(tt, lane)]      = 0.5f * h0v * (1.0f + erff(h0v * 0.70710678118654752f));
      G[swz(tt, lane + 64)] = 0.5f * h1v * (1.0f + erff(h1v * 0.70710678118654752f));
    }
  }
  __syncthreads();

  // ---- phase 3: decoder GEMM, wave = 16 h-rows x 64 tokens (lane = token) ----
  {
    float acc2[16];
#pragma unroll
    for (int j = 0; j < 16; ++j) acc2[j] = 0.0f;
    const float* wd = Wd + (size_t)e0 * EDIM;        // uniform -> s_load
#pragma unroll 4
    for (int e = 0; e < EDIM; ++e) {
      const float gv = G[swz(lane, e)];
#pragma unroll
      for (int j = 0; j < 16; ++j)
        acc2[j] = fmaf(gv, wd[(size_t)j * EDIM + e], acc2[j]);
    }
    // A is dead since phase-2 barrier; store logits (no alias with G)
#pragma unroll
    for (int j = 0; j < 16; ++j) A[swz(lane, e0 + j)] = acc2[j];
  }
  __syncthreads();

  // ---- phase 4: gumbel-sigmoid, exact top-k (value then lower-index), output ----
  for (int tt = wv * 8; tt < wv * 8 + 8; ++tt) {
    const size_t T = (size_t)(t0 + tt);
    const float l0 = A[swz(tt, lane)];
    const float l1 = A[swz(tt, lane + 64)];
    const float gn0 = gum[T * HDIM + lane];
    const float gn1 = gum[T * HDIM + lane + 64];
    const float z0 = (l0 + gn0 + 3.0f) * 2.5f;
    const float z1 = (l1 + gn1 + 3.0f) * 2.5f;
    const float ba0 = 1.0f / (1.0f + expf(-z0));
    const float ba1 = 1.0f / (1.0f + expf(-z1));
    const unsigned ub0 = __float_as_uint(ba0);       // ba in (0,1]: bits monotone
    const unsigned ub1 = __float_as_uint(ba1);
    const int r0 = ba0 > 0.5f;                       // round(ba): 0.5 rounds to 0
    const int r1 = ba1 > 0.5f;
    const int cnt = __popcll(__ballot(r0)) + __popcll(__ballot(r1));
    float bin0, bin1;
    if (cnt > 32) {
      // radix-select the 32nd-largest sigmoid value (on quantized fp32 bits)
      unsigned v = 0u;
#pragma unroll
      for (int b = 29; b >= 0; --b) {
        const unsigned cand = v | (1u << b);
        const int c = __popcll(__ballot(ub0 >= cand)) + __popcll(__ballot(ub1 >= cand));
        if (c >= 32) v = cand;
      }
      const int cgt = __popcll(__ballot(ub0 > v)) + __popcll(__ballot(ub1 > v));
      const int r = 32 - cgt;                        // tied slots; lower index wins
      const unsigned long long t0b = __ballot(ub0 == v);
      const unsigned long long t1b = __ballot(ub1 == v);
      const int n0 = __popcll(t0b);
      const unsigned long long mlt = (1ull << lane) - 1ull;
      const int rk0 = __popcll(t0b & mlt);
      const int rk1 = n0 + __popcll(t1b & mlt);
      bin0 = (ub0 > v || (ub0 == v && rk0 < r)) ? 1.0f : 0.0f;
      bin1 = (ub1 > v || (ub1 == v && rk1 < r)) ? 1.0f : 0.0f;
    } else if (cnt == 0) {
      float m = fmaxf(ba0, ba1);
#pragma unroll
      for (int mm = 32; mm; mm >>= 1) m = fmaxf(m, __shfl_xor(m, mm));
      const unsigned long long e0b = __ballot(ba0 == m);
      const unsigned long long e1b = __ballot(ba1 == m);
      const int hstar = e0b ? (__ffsll((unsigned long long)e0b) - 1)
                            : (64 + __ffsll((unsigned long long)e1b) - 1);
      bin0 = (lane == hstar) ? 1.0f : 0.0f;
      bin1 = (lane + 64 == hstar) ? 1.0f : 0.0f;
    } else {
      bin0 = r0 ? 1.0f : 0.0f;
      bin1 = r1 ? 1.0f : 0.0f;
    }
    outb[T * HDIM + lane]      = bin0;
    outb[T * HDIM + lane + 64] = bin1;
    outa[T * HDIM + lane]      = ba0;
    outa[T * HDIM + lane + 64] = ba1;
  }
}

extern "C" void kernel_launch(void* const* d_in, const int* in_sizes, int n_in,
                              void* d_out, int out_size, void* d_ws, size_t ws_size,
                              hipStream_t stream) {
  (void)in_sizes; (void)n_in; (void)d_ws; (void)ws_size; (void)out_size;
  const float* x   = (const float*)d_in[0];
  const float* Wr  = (const float*)d_in[1];
  const float* Wd  = (const float*)d_in[2];
  const float* gm  = (const float*)d_in[3];
  const float* bt  = (const float*)d_in[4];
  const float* rnn = (const float*)d_in[5];
  const float* gum = (const float*)d_in[6];
  float* outb = (float*)d_out;
  float* outa = outb + (size_t)NTOK * HDIM;   // tuple: (binary, binary_approx)
  fused_router<<<dim3(NTOK / TOKT), dim3(512), 0, stream>>>(
      x, Wr, Wd, gm, bt, rnn, gum, outb, outa);
}

// Round 2
// 454.351 us; speedup vs baseline: 1.1457x; 1.1457x over previous
//
#include <hip/hip_runtime.h>
#include <math.h>

#define NTOK   16384
#define DDIM   2048
#define EDIM   128
#define HDIM   128
#define TOKT   64
#define KT     128
#define NCH    (DDIM / KT)   // 16 k-chunks

// b32-granule XOR swizzle for A[64][128]: conflict-free for row access
// (fixed t, e=lane) and column access (t=lane, fixed e).
__device__ __forceinline__ int swz(int t, int e) {
  return t * EDIM + ((e & 96) | ((e ^ t) & 31));
}

__global__ __launch_bounds__(1024)
void fused_router(const float* __restrict__ x,
                  const float* __restrict__ Wr,
                  const float* __restrict__ Wd,
                  const float* __restrict__ gamma,
                  const float* __restrict__ beta,
                  const float* __restrict__ rnn,
                  const float* __restrict__ gum,
                  float* __restrict__ outb,
                  float* __restrict__ outa) {
  // sm: x-tile [64][128] during GEMM (float4 XOR-swizzled), then A (emb/logits,
  // b32 XOR-swizzled). g4: GELU output, float4 XOR-swizzled for b128 reads.
  __shared__ float sm[TOKT * KT];      // 32 KB
  __shared__ float g4[TOKT * EDIM];    // 32 KB

  const int tid  = (int)threadIdx.x;
  const int wv   = __builtin_amdgcn_readfirstlane(tid >> 6);  // 0..15
  const int lane = tid & 63;
  const int t0   = (int)blockIdx.x * TOKT;
  const int e0   = wv * 8;

  float acc[8];
#pragma unroll
  for (int j = 0; j < 8; ++j) acc[j] = 0.0f;

  // staging: 1024 threads x 2 float4 = 64 tokens x 128 k per chunk
  const int st_t = tid >> 5;          // 0..31  (i=1 adds 32)
  const int st_g = tid & 31;          // float4 group within row

  float4 pre[2];
#pragma unroll
  for (int i = 0; i < 2; ++i) {
    const int t = st_t + i * 32;
    pre[i] = *(const float4*)(x + (size_t)(t0 + t) * DDIM + st_g * 4);
  }

  for (int c = 0; c < NCH; ++c) {
    __syncthreads();                  // previous chunk's reads complete
#pragma unroll
    for (int i = 0; i < 2; ++i) {
      const int t = st_t + i * 32;
      *(float4*)&sm[t * KT + ((st_g ^ (t & 31)) << 2)] = pre[i];
    }
    if (c + 1 < NCH) {
#pragma unroll
      for (int i = 0; i < 2; ++i) {
        const int t = st_t + i * 32;
        pre[i] = *(const float4*)(x + (size_t)(t0 + t) * DDIM +
                                  (c + 1) * KT + st_g * 4);
      }
    }
    __syncthreads();

    // W rows for this wave, this chunk; uniform address -> s_load_dwordx4
    const float4* wb4 = (const float4*)(Wr + (size_t)e0 * DDIM) + c * (KT / 4);
#pragma unroll 2
    for (int kg = 0; kg < KT / 4; ++kg) {
      const float4 xv = *(const float4*)&sm[lane * KT + ((kg ^ (lane & 31)) << 2)];
#pragma unroll
      for (int j = 0; j < 8; ++j) {
        const float4 w = wb4[(size_t)j * (DDIM / 4) + kg];
        acc[j] = fmaf(xv.x, w.x,
                 fmaf(xv.y, w.y,
                 fmaf(xv.z, w.z,
                 fmaf(xv.w, w.w, acc[j]))));
      }
    }
  }
  __syncthreads();                    // xs dead; sm becomes A

  // ---- A fill: emb = router_out + rnn ----
#pragma unroll
  for (int j = 0; j < 8; ++j) sm[swz(lane, e0 + j)] = acc[j] + rnn[e0 + j];
  __syncthreads();

  // ---- LayerNorm + exact GELU: 4 tokens per wave; G -> g4 (float4-swizzled) ----
  {
    const float gm0 = gamma[lane], gm1 = gamma[lane + 64];
    const float bt0 = beta[lane],  bt1 = beta[lane + 64];
    for (int tt = wv * 4; tt < wv * 4 + 4; ++tt) {
      const float v0 = sm[swz(tt, lane)];
      const float v1 = sm[swz(tt, lane + 64)];
      float s = v0 + v1;
#pragma unroll
      for (int m = 32; m; m >>= 1) s += __shfl_xor(s, m);
      const float mu = s * (1.0f / 128.0f);
      const float d0 = v0 - mu, d1 = v1 - mu;
      float q = d0 * d0 + d1 * d1;
#pragma unroll
      for (int m = 32; m; m >>= 1) q += __shfl_xor(q, m);
      const float rstd = 1.0f / sqrtf(q * (1.0f / 128.0f) + 1e-5f);
      const float h0v = d0 * rstd * gm0 + bt0;
      const float h1v = d1 * rstd * gm1 + bt1;
      const float g0 = 0.5f * h0v * (1.0f + erff(h0v * 0.70710678118654752f));
      const float g1 = 0.5f * h1v * (1.0f + erff(h1v * 0.70710678118654752f));
      // e -> float4-swizzled slot: dword = (tt*32 + ((e>>2)^(tt&31)))*4 + (e&3)
      const int e0a = lane, e1a = lane + 64;
      g4[(tt * 32 + (((e0a >> 2) ^ (tt & 31)))) * 4 + (e0a & 3)] = g0;
      g4[(tt * 32 + (((e1a >> 2) ^ (tt & 31)))) * 4 + (e1a & 3)] = g1;
    }
  }
  __syncthreads();

  // ---- decoder GEMM: wave = 8 h-rows x 64 tokens (lane = token) ----
  {
    float acc2[8];
#pragma unroll
    for (int j = 0; j < 8; ++j) acc2[j] = 0.0f;
    const float4* wd4 = (const float4*)(Wd + (size_t)e0 * EDIM);  // uniform
#pragma unroll 2
    for (int kg = 0; kg < EDIM / 4; ++kg) {
      const float4 gv = *(const float4*)&g4[(lane * 32 + (kg ^ (lane & 31))) * 4];
#pragma unroll
      for (int j = 0; j < 8; ++j) {
        const float4 w = wd4[(size_t)j * (EDIM / 4) + kg];
        acc2[j] = fmaf(gv.x, w.x,
                  fmaf(gv.y, w.y,
                  fmaf(gv.z, w.z,
                  fmaf(gv.w, w.w, acc2[j]))));
      }
    }
    // A (emb) dead since LN read it; write logits (decoder read g4, not sm)
    __syncthreads();
#pragma unroll
    for (int j = 0; j < 8; ++j) sm[swz(lane, e0 + j)] = acc2[j];
  }
  __syncthreads();

  // ---- gumbel-sigmoid, exact top-k (value then lower-index), output ----
  for (int tt = wv * 4; tt < wv * 4 + 4; ++tt) {
    const size_t T = (size_t)(t0 + tt);
    const float l0 = sm[swz(tt, lane)];
    const float l1 = sm[swz(tt, lane + 64)];
    const float gn0 = gum[T * HDIM + lane];
    const float gn1 = gum[T * HDIM + lane + 64];
    const float z0 = (l0 + gn0 + 3.0f) * 2.5f;
    const float z1 = (l1 + gn1 + 3.0f) * 2.5f;
    const float ba0 = 1.0f / (1.0f + expf(-z0));
    const float ba1 = 1.0f / (1.0f + expf(-z1));
    const unsigned ub0 = __float_as_uint(ba0);   // ba in (0,1]: bits monotone
    const unsigned ub1 = __float_as_uint(ba1);
    const int r0 = ba0 > 0.5f;                   // round: 0.5 -> 0
    const int r1 = ba1 > 0.5f;
    const int cnt = __popcll(__ballot(r0)) + __popcll(__ballot(r1));
    float bin0, bin1;
    if (cnt > 32) {
      unsigned v = 0u;                            // radix-select 32nd largest
#pragma unroll
      for (int b = 29; b >= 0; --b) {
        const unsigned cand = v | (1u << b);
        const int c = __popcll(__ballot(ub0 >= cand)) + __popcll(__ballot(ub1 >= cand));
        if (c >= 32) v = cand;
      }
      const int cgt = __popcll(__ballot(ub0 > v)) + __popcll(__ballot(ub1 > v));
      const int r = 32 - cgt;                     // tied slots; lower index wins
      const unsigned long long t0b = __ballot(ub0 == v);
      const unsigned long long t1b = __ballot(ub1 == v);
      const int n0 = __popcll(t0b);
      const unsigned long long mlt = (1ull << lane) - 1ull;
      const int rk0 = __popcll(t0b & mlt);
      const int rk1 = n0 + __popcll(t1b & mlt);
      bin0 = (ub0 > v || (ub0 == v && rk0 < r)) ? 1.0f : 0.0f;
      bin1 = (ub1 > v || (ub1 == v && rk1 < r)) ? 1.0f : 0.0f;
    } else if (cnt == 0) {
      float m = fmaxf(ba0, ba1);
#pragma unroll
      for (int mm = 32; mm; mm >>= 1) m = fmaxf(m, __shfl_xor(m, mm));
      const unsigned long long e0b = __ballot(ba0 == m);
      const unsigned long long e1b = __ballot(ba1 == m);
      const int hstar = e0b ? (__ffsll((unsigned long long)e0b) - 1)
                            : (64 + __ffsll((unsigned long long)e1b) - 1);
      bin0 = (lane == hstar) ? 1.0f : 0.0f;
      bin1 = (lane + 64 == hstar) ? 1.0f : 0.0f;
    } else {
      bin0 = r0 ? 1.0f : 0.0f;
      bin1 = r1 ? 1.0f : 0.0f;
    }
    outb[T * HDIM + lane]      = bin0;
    outb[T * HDIM + lane + 64] = bin1;
    outa[T * HDIM + lane]      = ba0;
    outa[T * HDIM + lane + 64] = ba1;
  }
}

extern "C" void kernel_launch(void* const* d_in, const int* in_sizes, int n_in,
                              void* d_out, int out_size, void* d_ws, size_t ws_size,
                              hipStream_t stream) {
  (void)in_sizes; (void)n_in; (void)d_ws; (void)ws_size; (void)out_size;
  const float* x   = (const float*)d_in[0];
  const float* Wr  = (const float*)d_in[1];
  const float* Wd  = (const float*)d_in[2];
  const float* gm  = (const float*)d_in[3];
  const float* bt  = (const float*)d_in[4];
  const float* rnn = (const float*)d_in[5];
  const float* gum = (const float*)d_in[6];
  float* outb = (float*)d_out;
  float* outa = outb + (size_t)NTOK * HDIM;   // tuple: (binary, binary_approx)
  fused_router<<<dim3(NTOK / TOKT), dim3(1024), 0, stream>>>(
      x, Wr, Wd, gm, bt, rnn, gum, outb, outa);
}

// Round 3
// 304.898 us; speedup vs baseline: 1.7073x; 1.4902x over previous
//
#include <hip/hip_runtime.h>
#include <math.h>

#define NTOK   16384
#define DDIM   2048
#define EDIM   128
#define HDIM   128
#define TOKT   64
#define KC     64
#define NCH    (DDIM / KC)   // 32 chunks

// b32-granule XOR swizzle for epilogue A[64][128]: conflict-free row+column.
__device__ __forceinline__ int swz(int t, int e) {
  return t * EDIM + ((e & 96) | ((e ^ t) & 31));
}

// Main-loop LDS layouts (per 64-k chunk), XOR-octet/quad swizzled so that
// per-k vector reads AND transpose staging writes are (near) conflict-free:
//   xT element (k,t): k*64  + (((t>>3) ^ ((k>>2)&7)) << 3) + (t&7)
//   wT element (k,e): k*128 + (((e>>2) ^ ((k>>2)&7)) << 2) + (e&3)

__global__ __launch_bounds__(1024)
void fused_router(const float* __restrict__ x,
                  const float* __restrict__ Wr,
                  const float* __restrict__ Wd,
                  const float* __restrict__ gamma,
                  const float* __restrict__ beta,
                  const float* __restrict__ rnn,
                  const float* __restrict__ gum,
                  float* __restrict__ outb,
                  float* __restrict__ outa) {
  __shared__ float lds[16384];          // 64 KB
  float* const xT  = lds;               // [64k][64t]   16 KB (GEMM phase)
  float* const wT  = lds + 4096;        // [64k][128e]  32 KB (GEMM phase)
  float* const A   = lds;               // [64][128] swz     (epilogue)
  float* const G4  = lds + 8192;        // [64][128] f4-swz  (epilogue)
  float* const buf0 = lds;              // k-reduction exchange
  float* const buf1 = lds + 8192;

  const int tid  = (int)threadIdx.x;
  const int wv   = __builtin_amdgcn_readfirstlane(tid >> 6);  // 0..15
  const int lane = tid & 63;
  const int t0   = (int)blockIdx.x * TOKT;

  // main-loop wave/lane tiling: wave = (k-quarter, e-range of 32),
  // lane = (token octet, e quad) -> 8x4 register tile
  const int kq = wv & 3;
  const int eq = wv >> 2;
  const int t8 = lane & 7;
  const int e8 = lane >> 3;
  const int ebase = eq * 32 + e8 * 4;

  // staging maps (coalesced global float4 reads)
  const int xt_t = tid >> 4;            // 0..63 token
  const int xt_k = tid & 15;            // k-group (*4)
  const int wt_e = tid >> 3;            // 0..127 e-row
  const int wt_k = tid & 7;             // k-group (*4), second half +8

  float acc[8][4];
#pragma unroll
  for (int i = 0; i < 8; ++i)
#pragma unroll
    for (int j = 0; j < 4; ++j) acc[i][j] = 0.0f;

  const float* xg = x  + (size_t)(t0 + xt_t) * DDIM + xt_k * 4;
  const float* wg = Wr + (size_t)wt_e * DDIM + wt_k * 4;
  float4 px  = *(const float4*)xg;
  float4 pw0 = *(const float4*)wg;
  float4 pw1 = *(const float4*)(wg + 32);

  for (int c = 0; c < NCH; ++c) {
    __syncthreads();                    // previous chunk's reads complete
    {
      const int xo = (((xt_t >> 3) ^ (xt_k & 7)) << 3) + (xt_t & 7);
      float* p = xT + xt_k * 4 * 64 + xo;         // consecutive k: +64
      p[0] = px.x; p[64] = px.y; p[128] = px.z; p[192] = px.w;
    }
    {
      const int wo = (((wt_e >> 2) ^ wt_k) << 2) + (wt_e & 3);
      float* p0 = wT + wt_k * 4 * 128 + wo;       // consecutive k: +128
      p0[0] = pw0.x; p0[128] = pw0.y; p0[256] = pw0.z; p0[384] = pw0.w;
      float* p1 = p0 + 4096;                      // k += 32 (same swizzle)
      p1[0] = pw1.x; p1[128] = pw1.y; p1[256] = pw1.z; p1[384] = pw1.w;
    }
    if (c + 1 < NCH) {
      px  = *(const float4*)(xg + (c + 1) * KC);
      pw0 = *(const float4*)(wg + (c + 1) * KC);
      pw1 = *(const float4*)(wg + (c + 1) * KC + 32);
    }
    __syncthreads();

    const int kb = kq * 16;
#pragma unroll 4
    for (int kk = 0; kk < 16; ++kk) {
      const int k = kb + kk;
      const int s = (k >> 2) & 7;
      const float* xr = xT + k * 64 + ((t8 ^ s) << 3);
      const float4 a0 = *(const float4*)xr;
      const float4 a1 = *(const float4*)(xr + 4);
      const float4 b  = *(const float4*)(wT + k * 128 + ((((ebase >> 2) ^ s)) << 2));
#pragma unroll
      for (int i = 0; i < 8; ++i) {
        const float av = (i < 4) ? (&a0.x)[i] : (&a1.x)[i - 4];
        acc[i][0] = fmaf(av, b.x, acc[i][0]);
        acc[i][1] = fmaf(av, b.y, acc[i][1]);
        acc[i][2] = fmaf(av, b.z, acc[i][2]);
        acc[i][3] = fmaf(av, b.w, acc[i][3]);
      }
    }
  }

  // ---- k-reduction across the 4 k-quarters (LDS exchange) ----
  __syncthreads();                       // GEMM tiles dead
  if (kq == 1) {
#pragma unroll
    for (int i = 0; i < 8; ++i)
#pragma unroll
      for (int j = 0; j < 4; ++j) buf0[swz(t8 * 8 + i, ebase + j)] = acc[i][j];
  } else if (kq == 3) {
#pragma unroll
    for (int i = 0; i < 8; ++i)
#pragma unroll
      for (int j = 0; j < 4; ++j) buf1[swz(t8 * 8 + i, ebase + j)] = acc[i][j];
  }
  __syncthreads();
  if (kq == 0) {
#pragma unroll
    for (int i = 0; i < 8; ++i)
#pragma unroll
      for (int j = 0; j < 4; ++j) acc[i][j] += buf0[swz(t8 * 8 + i, ebase + j)];
  } else if (kq == 2) {
#pragma unroll
    for (int i = 0; i < 8; ++i)
#pragma unroll
      for (int j = 0; j < 4; ++j) acc[i][j] += buf1[swz(t8 * 8 + i, ebase + j)];
  }
  __syncthreads();
  if (kq == 2) {
#pragma unroll
    for (int i = 0; i < 8; ++i)
#pragma unroll
      for (int j = 0; j < 4; ++j) buf0[swz(t8 * 8 + i, ebase + j)] = acc[i][j];
  }
  __syncthreads();
  if (kq == 0) {
    const float4 rv = *(const float4*)(rnn + ebase);
#pragma unroll
    for (int i = 0; i < 8; ++i)
#pragma unroll
      for (int j = 0; j < 4; ++j) {
        const float full = acc[i][j] + buf0[swz(t8 * 8 + i, ebase + j)] + (&rv.x)[j];
        A[swz(t8 * 8 + i, ebase + j)] = full;    // same slots this lane read
      }
  }
  __syncthreads();

  // ---- LayerNorm + exact GELU: 4 tokens per wave; G -> G4 (float4-swizzled) ----
  const int e0 = wv * 8;                 // epilogue e-mapping (16 waves x 8)
  {
    const float gm0 = gamma[lane], gm1 = gamma[lane + 64];
    const float bt0 = beta[lane],  bt1 = beta[lane + 64];
    for (int tt = wv * 4; tt < wv * 4 + 4; ++tt) {
      const float v0 = A[swz(tt, lane)];
      const float v1 = A[swz(tt, lane + 64)];
      float s = v0 + v1;
#pragma unroll
      for (int m = 32; m; m >>= 1) s += __shfl_xor(s, m);
      const float mu = s * (1.0f / 128.0f);
      const float d0 = v0 - mu, d1 = v1 - mu;
      float q = d0 * d0 + d1 * d1;
#pragma unroll
      for (int m = 32; m; m >>= 1) q += __shfl_xor(q, m);
      const float rstd = 1.0f / sqrtf(q * (1.0f / 128.0f) + 1e-5f);
      const float h0v = d0 * rstd * gm0 + bt0;
      const float h1v = d1 * rstd * gm1 + bt1;
      const float g0 = 0.5f * h0v * (1.0f + erff(h0v * 0.70710678118654752f));
      const float g1 = 0.5f * h1v * (1.0f + erff(h1v * 0.70710678118654752f));
      const int e0a = lane, e1a = lane + 64;
      G4[(tt * 32 + (((e0a >> 2) ^ (tt & 31)))) * 4 + (e0a & 3)] = g0;
      G4[(tt * 32 + (((e1a >> 2) ^ (tt & 31)))) * 4 + (e1a & 3)] = g1;
    }
  }
  __syncthreads();

  // ---- decoder GEMM: wave = 8 h-rows x 64 tokens (lane = token) ----
  {
    float acc2[8];
#pragma unroll
    for (int j = 0; j < 8; ++j) acc2[j] = 0.0f;
    const float4* wd4 = (const float4*)(Wd + (size_t)e0 * EDIM);  // uniform
#pragma unroll 2
    for (int kg = 0; kg < EDIM / 4; ++kg) {
      const float4 gv = *(const float4*)&G4[(lane * 32 + (kg ^ (lane & 31))) * 4];
#pragma unroll
      for (int j = 0; j < 8; ++j) {
        const float4 w = wd4[(size_t)j * (EDIM / 4) + kg];
        acc2[j] = fmaf(gv.x, w.x,
                  fmaf(gv.y, w.y,
                  fmaf(gv.z, w.z,
                  fmaf(gv.w, w.w, acc2[j]))));
      }
    }
    __syncthreads();
#pragma unroll
    for (int j = 0; j < 8; ++j) A[swz(lane, e0 + j)] = acc2[j];
  }
  __syncthreads();

  // ---- gumbel-sigmoid, exact top-k (value then lower-index), output ----
  for (int tt = wv * 4; tt < wv * 4 + 4; ++tt) {
    const size_t T = (size_t)(t0 + tt);
    const float l0 = A[swz(tt, lane)];
    const float l1 = A[swz(tt, lane + 64)];
    const float gn0 = gum[T * HDIM + lane];
    const float gn1 = gum[T * HDIM + lane + 64];
    const float z0 = (l0 + gn0 + 3.0f) * 2.5f;
    const float z1 = (l1 + gn1 + 3.0f) * 2.5f;
    const float ba0 = 1.0f / (1.0f + expf(-z0));
    const float ba1 = 1.0f / (1.0f + expf(-z1));
    const unsigned ub0 = __float_as_uint(ba0);   // ba in (0,1]: bits monotone
    const unsigned ub1 = __float_as_uint(ba1);
    const int r0 = ba0 > 0.5f;                   // round: 0.5 -> 0
    const int r1 = ba1 > 0.5f;
    const int cnt = __popcll(__ballot(r0)) + __popcll(__ballot(r1));
    float bin0, bin1;
    if (cnt > 32) {
      unsigned v = 0u;                            // radix-select 32nd largest
#pragma unroll
      for (int b = 29; b >= 0; --b) {
        const unsigned cand = v | (1u << b);
        const int cc = __popcll(__ballot(ub0 >= cand)) + __popcll(__ballot(ub1 >= cand));
        if (cc >= 32) v = cand;
      }
      const int cgt = __popcll(__ballot(ub0 > v)) + __popcll(__ballot(ub1 > v));
      const int r = 32 - cgt;                     // tied slots; lower index wins
      const unsigned long long t0b = __ballot(ub0 == v);
      const unsigned long long t1b = __ballot(ub1 == v);
      const int n0 = __popcll(t0b);
      const unsigned long long mlt = (1ull << lane) - 1ull;
      const int rk0 = __popcll(t0b & mlt);
      const int rk1 = n0 + __popcll(t1b & mlt);
      bin0 = (ub0 > v || (ub0 == v && rk0 < r)) ? 1.0f : 0.0f;
      bin1 = (ub1 > v || (ub1 == v && rk1 < r)) ? 1.0f : 0.0f;
    } else if (cnt == 0) {
      float m = fmaxf(ba0, ba1);
#pragma unroll
      for (int mm = 32; mm; mm >>= 1) m = fmaxf(m, __shfl_xor(m, mm));
      const unsigned long long e0b = __ballot(ba0 == m);
      const unsigned long long e1b = __ballot(ba1 == m);
      const int hstar = e0b ? (__ffsll((unsigned long long)e0b) - 1)
                            : (64 + __ffsll((unsigned long long)e1b) - 1);
      bin0 = (lane == hstar) ? 1.0f : 0.0f;
      bin1 = (lane + 64 == hstar) ? 1.0f : 0.0f;
    } else {
      bin0 = r0 ? 1.0f : 0.0f;
      bin1 = r1 ? 1.0f : 0.0f;
    }
    outb[T * HDIM + lane]      = bin0;
    outb[T * HDIM + lane + 64] = bin1;
    outa[T * HDIM + lane]      = ba0;
    outa[T * HDIM + lane + 64] = ba1;
  }
}

extern "C" void kernel_launch(void* const* d_in, const int* in_sizes, int n_in,
                              void* d_out, int out_size, void* d_ws, size_t ws_size,
                              hipStream_t stream) {
  (void)in_sizes; (void)n_in; (void)d_ws; (void)ws_size; (void)out_size;
  const float* x   = (const float*)d_in[0];
  const float* Wr  = (const float*)d_in[1];
  const float* Wd  = (const float*)d_in[2];
  const float* gm  = (const float*)d_in[3];
  const float* bt  = (const float*)d_in[4];
  const float* rnn = (const float*)d_in[5];
  const float* gum = (const float*)d_in[6];
  float* outb = (float*)d_out;
  float* outa = outb + (size_t)NTOK * HDIM;   // tuple: (binary, binary_approx)
  fused_router<<<dim3(NTOK / TOKT), dim3(1024), 0, stream>>>(
      x, Wr, gm ? Wd : Wd, gm, bt, rnn, gum, outb, outa);
}

// Round 4
// 262.422 us; speedup vs baseline: 1.9837x; 1.1619x over previous
//
#include <hip/hip_runtime.h>
#include <math.h>

#define NTOK   16384
#define DDIM   2048
#define EDIM   128
#define HDIM   128
#define TOKT   64
#define KC     64
#define NCH    (DDIM / KC)   // 32 chunks

typedef __attribute__((ext_vector_type(8))) _Float16 half8;
typedef __attribute__((ext_vector_type(4))) _Float16 half4;
typedef __attribute__((ext_vector_type(4))) float    f32x4;

// b32-granule XOR swizzle for epilogue A[64][128]: conflict-free row+column.
__device__ __forceinline__ int swz(int t, int e) {
  return t * EDIM + ((e & 96) | ((e ^ t) & 31));
}

// ---- W pre-convert: fragment-ordered f16 hi/lo planes in workspace ----
// frag-row idx -> (nt, ks, lane); lane holds B[k=ks*32+(lane>>4)*8+j][n=nt*16+(lane&15)]
// = Wr[n][k], scaled by 32 (hi) and 32*2048 (lo) to dodge f16 denormals.
__global__ __launch_bounds__(256)
void conv_w(const float* __restrict__ Wr,
            _Float16* __restrict__ wh, _Float16* __restrict__ wl) {
  const int idx  = (int)blockIdx.x * 256 + (int)threadIdx.x;  // 0..32767
  const int lane = idx & 63;
  const int ks   = (idx >> 6) & 63;
  const int nt   = idx >> 12;
  const int n    = nt * 16 + (lane & 15);
  const int k0   = ks * 32 + (lane >> 4) * 8;
  half8 h, l;
#pragma unroll
  for (int j = 0; j < 8; ++j) {
    const float w = Wr[(size_t)n * DDIM + k0 + j] * 32.0f;
    const _Float16 hh = (_Float16)w;
    h[j] = hh;
    l[j] = (_Float16)((w - (float)hh) * 2048.0f);
  }
  *(half8*)(wh + (size_t)idx * 8) = h;
  *(half8*)(wl + (size_t)idx * 8) = l;
}

__global__ __launch_bounds__(1024)
void fused_router(const float* __restrict__ x,
                  const _Float16* __restrict__ wsh,
                  const _Float16* __restrict__ wsl,
                  const float* __restrict__ Wd,
                  const float* __restrict__ gamma,
                  const float* __restrict__ beta,
                  const float* __restrict__ rnn,
                  const float* __restrict__ gum,
                  float* __restrict__ outb,
                  float* __restrict__ outa) {
  __shared__ char smraw[65536];
  _Float16* const xh = (_Float16*)smraw;          // [2][64t][64k] f16 hi, 16 KB
  _Float16* const xl = xh + 8192;                 // [2][64t][64k] f16 lo, 16 KB
  float* const A  = (float*)smraw;                // epilogue [64][128] swz, 32 KB
  float* const G4 = (float*)(smraw + 32768);      // epilogue f4-swz, 32 KB

  const int tid  = (int)threadIdx.x;
  const int wv   = __builtin_amdgcn_readfirstlane(tid >> 6);  // 0..15
  const int lane = tid & 63;
  const int t0   = (int)blockIdx.x * TOKT;

  // MFMA tiling: wave -> m-tile (16 tok) + 2 n-tiles (16 e each); full K per wave.
  const int mt   = wv & 3;
  const int nt0  = (wv >> 2) * 2;
  const int mrow = lane & 15;
  const int quad = lane >> 4;
  const int tloc = mt * 16 + (lane & 15);         // A-frag token row

  // x staging map: thread -> (t, 4 consecutive k)
  const int st_t = tid >> 4;                      // 0..63
  const int st_k = tid & 15;                      // *4
  // LDS f16 idx for the 4-value write (granule-XOR swizzle)
  const int wofs = st_t * 64 + (((st_k >> 1) ^ (st_t & 7)) << 3) + ((st_k & 1) << 2);
  // A-frag read offsets for k-steps 0/1 within a chunk
  const int offA0 = tloc * 64 + (((0 * 4 + quad) ^ (tloc & 7)) << 3);
  const int offA1 = tloc * 64 + (((1 * 4 + quad) ^ (tloc & 7)) << 3);

  f32x4 hh0 = {0,0,0,0}, cr0 = {0,0,0,0}, hh1 = {0,0,0,0}, cr1 = {0,0,0,0};

  const float* xg = x + (size_t)(t0 + st_t) * DDIM + st_k * 4;
  float4 px = *(const float4*)xg;

  // preamble: stage chunk 0 into buf 0
  {
    half4 hv, lv;
#pragma unroll
    for (int m = 0; m < 4; ++m) {
      const float v = (&px.x)[m];
      const _Float16 h = (_Float16)v;
      hv[m] = h;
      lv[m] = (_Float16)((v - (float)h) * 2048.0f);
    }
    *(half4*)&xh[wofs] = hv;
    *(half4*)&xl[wofs] = lv;
  }

  for (int c = 0; c < NCH; ++c) {
    __syncthreads();                              // buf[c&1] writes visible
    if (c + 1 < NCH) px = *(const float4*)(xg + (c + 1) * KC);

    const int bo = (c & 1) * 4096;
    const int ks0 = c * 2;
#pragma unroll
    for (int s = 0; s < 2; ++s) {
      const int ks = ks0 + s;
      const half8 ah = *(const half8*)&xh[bo + (s ? offA1 : offA0)];
      const half8 al = *(const half8*)&xl[bo + (s ? offA1 : offA0)];
      const half8 bh0 = *(const half8*)(wsh + ((size_t)((nt0    ) * 64 + ks) * 64 + lane) * 8);
      const half8 bl0 = *(const half8*)(wsl + ((size_t)((nt0    ) * 64 + ks) * 64 + lane) * 8);
      const half8 bh1 = *(const half8*)(wsh + ((size_t)((nt0 + 1) * 64 + ks) * 64 + lane) * 8);
      const half8 bl1 = *(const half8*)(wsl + ((size_t)((nt0 + 1) * 64 + ks) * 64 + lane) * 8);
      hh0 = __builtin_amdgcn_mfma_f32_16x16x32_f16(ah, bh0, hh0, 0, 0, 0);
      cr0 = __builtin_amdgcn_mfma_f32_16x16x32_f16(ah, bl0, cr0, 0, 0, 0);
      cr0 = __builtin_amdgcn_mfma_f32_16x16x32_f16(al, bh0, cr0, 0, 0, 0);
      hh1 = __builtin_amdgcn_mfma_f32_16x16x32_f16(ah, bh1, hh1, 0, 0, 0);
      cr1 = __builtin_amdgcn_mfma_f32_16x16x32_f16(ah, bl1, cr1, 0, 0, 0);
      cr1 = __builtin_amdgcn_mfma_f32_16x16x32_f16(al, bh1, cr1, 0, 0, 0);
    }

    if (c + 1 < NCH) {                            // convert + write other buffer
      half4 hv, lv;
#pragma unroll
      for (int m = 0; m < 4; ++m) {
        const float v = (&px.x)[m];
        const _Float16 h = (_Float16)v;
        hv[m] = h;
        lv[m] = (_Float16)((v - (float)h) * 2048.0f);
      }
      *(half4*)&xh[((c + 1) & 1) * 4096 + wofs] = hv;
      *(half4*)&xl[((c + 1) & 1) * 4096 + wofs] = lv;
    }
  }

  // ---- unscale, add rnn, write emb to epilogue A (C/D: col=lane&15, row=quad*4+r) ----
  __syncthreads();                                // all LDS reads of x bufs done
  {
    const int e0e = nt0 * 16 + mrow;
    const int e1e = (nt0 + 1) * 16 + mrow;
    const float r0v = rnn[e0e], r1v = rnn[e1e];
#pragma unroll
    for (int r = 0; r < 4; ++r) {
      const int tt = mt * 16 + quad * 4 + r;
      A[swz(tt, e0e)] = hh0[r] * (1.0f / 32.0f) + cr0[r] * (1.0f / 65536.0f) + r0v;
      A[swz(tt, e1e)] = hh1[r] * (1.0f / 32.0f) + cr1[r] * (1.0f / 65536.0f) + r1v;
    }
  }
  __syncthreads();

  // ---- LayerNorm + exact GELU: 4 tokens per wave; G -> G4 (float4-swizzled) ----
  const int e0 = wv * 8;                          // epilogue e-mapping
  {
    const float gm0 = gamma[lane], gm1 = gamma[lane + 64];
    const float bt0 = beta[lane],  bt1 = beta[lane + 64];
    for (int tt = wv * 4; tt < wv * 4 + 4; ++tt) {
      const float v0 = A[swz(tt, lane)];
      const float v1 = A[swz(tt, lane + 64)];
      float s = v0 + v1;
#pragma unroll
      for (int m = 32; m; m >>= 1) s += __shfl_xor(s, m);
      const float mu = s * (1.0f / 128.0f);
      const float d0 = v0 - mu, d1 = v1 - mu;
      float q = d0 * d0 + d1 * d1;
#pragma unroll
      for (int m = 32; m; m >>= 1) q += __shfl_xor(q, m);
      const float rstd = 1.0f / sqrtf(q * (1.0f / 128.0f) + 1e-5f);
      const float h0v = d0 * rstd * gm0 + bt0;
      const float h1v = d1 * rstd * gm1 + bt1;
      const float g0 = 0.5f * h0v * (1.0f + erff(h0v * 0.70710678118654752f));
      const float g1 = 0.5f * h1v * (1.0f + erff(h1v * 0.70710678118654752f));
      const int e0a = lane, e1a = lane + 64;
      G4[(tt * 32 + (((e0a >> 2) ^ (tt & 31)))) * 4 + (e0a & 3)] = g0;
      G4[(tt * 32 + (((e1a >> 2) ^ (tt & 31)))) * 4 + (e1a & 3)] = g1;
    }
  }
  __syncthreads();

  // ---- decoder GEMM: wave = 8 h-rows x 64 tokens (lane = token) ----
  {
    float acc2[8];
#pragma unroll
    for (int j = 0; j < 8; ++j) acc2[j] = 0.0f;
    const float4* wd4 = (const float4*)(Wd + (size_t)e0 * EDIM);  // uniform
#pragma unroll 2
    for (int kg = 0; kg < EDIM / 4; ++kg) {
      const float4 gv = *(const float4*)&G4[(lane * 32 + (kg ^ (lane & 31))) * 4];
#pragma unroll
      for (int j = 0; j < 8; ++j) {
        const float4 w = wd4[(size_t)j * (EDIM / 4) + kg];
        acc2[j] = fmaf(gv.x, w.x,
                  fmaf(gv.y, w.y,
                  fmaf(gv.z, w.z,
                  fmaf(gv.w, w.w, acc2[j]))));
      }
    }
    __syncthreads();
#pragma unroll
    for (int j = 0; j < 8; ++j) A[swz(lane, e0 + j)] = acc2[j];
  }
  __syncthreads();

  // ---- gumbel-sigmoid, exact top-k (value then lower-index), output ----
  for (int tt = wv * 4; tt < wv * 4 + 4; ++tt) {
    const size_t T = (size_t)(t0 + tt);
    const float l0 = A[swz(tt, lane)];
    const float l1 = A[swz(tt, lane + 64)];
    const float gn0 = gum[T * HDIM + lane];
    const float gn1 = gum[T * HDIM + lane + 64];
    const float z0 = (l0 + gn0 + 3.0f) * 2.5f;
    const float z1 = (l1 + gn1 + 3.0f) * 2.5f;
    const float ba0 = 1.0f / (1.0f + expf(-z0));
    const float ba1 = 1.0f / (1.0f + expf(-z1));
    const unsigned ub0 = __float_as_uint(ba0);   // ba in (0,1]: bits monotone
    const unsigned ub1 = __float_as_uint(ba1);
    const int r0 = ba0 > 0.5f;                   // round: 0.5 -> 0
    const int r1 = ba1 > 0.5f;
    const int cnt = __popcll(__ballot(r0)) + __popcll(__ballot(r1));
    float bin0, bin1;
    if (cnt > 32) {
      unsigned v = 0u;                            // radix-select 32nd largest
#pragma unroll
      for (int b = 29; b >= 0; --b) {
        const unsigned cand = v | (1u << b);
        const int cc = __popcll(__ballot(ub0 >= cand)) + __popcll(__ballot(ub1 >= cand));
        if (cc >= 32) v = cand;
      }
      const int cgt = __popcll(__ballot(ub0 > v)) + __popcll(__ballot(ub1 > v));
      const int r = 32 - cgt;                     // tied slots; lower index wins
      const unsigned long long t0b = __ballot(ub0 == v);
      const unsigned long long t1b = __ballot(ub1 == v);
      const int n0 = __popcll(t0b);
      const unsigned long long mlt = (1ull << lane) - 1ull;
      const int rk0 = __popcll(t0b & mlt);
      const int rk1 = n0 + __popcll(t1b & mlt);
      bin0 = (ub0 > v || (ub0 == v && rk0 < r)) ? 1.0f : 0.0f;
      bin1 = (ub1 > v || (ub1 == v && rk1 < r)) ? 1.0f : 0.0f;
    } else if (cnt == 0) {
      float m = fmaxf(ba0, ba1);
#pragma unroll
      for (int mm = 32; mm; mm >>= 1) m = fmaxf(m, __shfl_xor(m, mm));
      const unsigned long long e0b = __ballot(ba0 == m);
      const unsigned long long e1b = __ballot(ba1 == m);
      const int hstar = e0b ? (__ffsll((unsigned long long)e0b) - 1)
                            : (64 + __ffsll((unsigned long long)e1b) - 1);
      bin0 = (lane == hstar) ? 1.0f : 0.0f;
      bin1 = (lane + 64 == hstar) ? 1.0f : 0.0f;
    } else {
      bin0 = r0 ? 1.0f : 0.0f;
      bin1 = r1 ? 1.0f : 0.0f;
    }
    outb[T * HDIM + lane]      = bin0;
    outb[T * HDIM + lane + 64] = bin1;
    outa[T * HDIM + lane]      = ba0;
    outa[T * HDIM + lane + 64] = ba1;
  }
}

extern "C" void kernel_launch(void* const* d_in, const int* in_sizes, int n_in,
                              void* d_out, int out_size, void* d_ws, size_t ws_size,
                              hipStream_t stream) {
  (void)in_sizes; (void)n_in; (void)ws_size; (void)out_size;
  const float* x   = (const float*)d_in[0];
  const float* Wr  = (const float*)d_in[1];
  const float* Wd  = (const float*)d_in[2];
  const float* gm  = (const float*)d_in[3];
  const float* bt  = (const float*)d_in[4];
  const float* rnn = (const float*)d_in[5];
  const float* gum = (const float*)d_in[6];
  float* outb = (float*)d_out;
  float* outa = outb + (size_t)NTOK * HDIM;   // tuple: (binary, binary_approx)

  _Float16* wh = (_Float16*)d_ws;             // 512 KB
  _Float16* wl = wh + (size_t)EDIM * DDIM;    // 512 KB

  conv_w<<<dim3(128), dim3(256), 0, stream>>>(Wr, wh, wl);
  fused_router<<<dim3(NTOK / TOKT), dim3(1024), 0, stream>>>(
      x, wh, wl, Wd, gm, bt, rnn, gum, outb, outa);
}

// Round 5
// 259.666 us; speedup vs baseline: 2.0047x; 1.0106x over previous
//
#include <hip/hip_runtime.h>
#include <math.h>

#define NTOK   16384
#define DDIM   2048
#define EDIM   128
#define HDIM   128
#define TOKT   64
#define KC     32
#define NCH    (DDIM / KC)   // 64 chunks of 32 k

typedef __attribute__((ext_vector_type(8))) _Float16 half8;
typedef __attribute__((ext_vector_type(4))) float    f32x4;

// b32-granule XOR swizzle for epilogue A[64][128]: conflict-free row+column.
__device__ __forceinline__ int swz(int t, int e) {
  return t * EDIM + ((e & 96) | ((e ^ t) & 31));
}

// ---- W pre-convert: fragment-ordered f16 hi/lo planes in workspace ----
// frag idx -> (nt, ks, lane); lane holds B[k=ks*32+(lane>>4)*8+j][n=nt*16+(lane&15)]
// = Wr[n][k], scaled by 32 (hi) and 32*2048 (lo) to dodge f16 denormals.
__global__ __launch_bounds__(256)
void conv_w(const float* __restrict__ Wr,
            _Float16* __restrict__ wh, _Float16* __restrict__ wl) {
  const int idx  = (int)blockIdx.x * 256 + (int)threadIdx.x;  // 0..32767
  const int lane = idx & 63;
  const int ks   = (idx >> 6) & 63;
  const int nt   = idx >> 12;
  const int n    = nt * 16 + (lane & 15);
  const int k0   = ks * 32 + (lane >> 4) * 8;
  half8 h, l;
#pragma unroll
  for (int j = 0; j < 8; ++j) {
    const float w = Wr[(size_t)n * DDIM + k0 + j] * 32.0f;
    const _Float16 hh = (_Float16)w;
    h[j] = hh;
    l[j] = (_Float16)((w - (float)hh) * 2048.0f);
  }
  *(half8*)(wh + (size_t)idx * 8) = h;
  *(half8*)(wl + (size_t)idx * 8) = l;
}

__global__ __launch_bounds__(1024)
void fused_router(const float* __restrict__ x,
                  const _Float16* __restrict__ wsh,
                  const _Float16* __restrict__ wsl,
                  const float* __restrict__ Wd,
                  const float* __restrict__ gamma,
                  const float* __restrict__ beta,
                  const float* __restrict__ rnn,
                  const float* __restrict__ gum,
                  float* __restrict__ outb,
                  float* __restrict__ outa) {
  // GEMM phase (halves index space xs):
  //   x bufs:  b*4096  + p*2048 + (mt*64+lane)*8          (2 x 8 KB)
  //   W bufs:  8192 + b*8192 + (nt*2+p)*512 + lane*8      (2 x 16 KB)
  // Epilogue: A = bytes [0,32K), G4 = bytes [32K,64K)
  __shared__ char smraw[65536];
  _Float16* const xs = (_Float16*)smraw;
  float* const A  = (float*)smraw;
  float* const G4 = (float*)(smraw + 32768);

  const int tid  = (int)threadIdx.x;
  const int wv   = __builtin_amdgcn_readfirstlane(tid >> 6);  // 0..15
  const int lane = tid & 63;
  const int t0   = (int)blockIdx.x * TOKT;

  // MFMA mapping: wave = 2 m-tiles x 1 n-tile, full K per wave.
  const int nt   = wv & 7;
  const int mt0  = (wv >> 3) * 2;
  const int mt1  = mt0 + 1;
  const int quad = lane >> 4;
  const int col  = lane & 15;

  const int offA0 = (mt0 * 64 + lane) * 8;          // + b*4096 (+2048 lo)
  const int offA1 = (mt1 * 64 + lane) * 8;
  const int offB  = 8192 + nt * 1024 + lane * 8;    // + b*8192 (+512 lo)

  // x staging: waves 0..3 (256 thr), thread -> (token, 8 consecutive k)
  const bool xstage = tid < 256;
  const int  sx_t   = tid >> 2;
  const int  sx_kq  = tid & 3;
  const float* xg   = x + (size_t)(t0 + sx_t) * DDIM + sx_kq * 8;
  const int  sx_off = ((sx_t >> 4) * 64 + sx_kq * 16 + (sx_t & 15)) * 8;

  // W staging: waves 8..15, wave -> one n-tile (hi+lo segs, 1 KB each)
  const bool wstage = wv >= 8;
  const int  ntw    = wv & 7;
  const _Float16* whg = wsh + (size_t)ntw * 32768 + (size_t)lane * 8;  // +c*512
  const _Float16* wlg = wsl + (size_t)ntw * 32768 + (size_t)lane * 8;
  const int  sw_off = 8192 + ntw * 1024 + lane * 8;  // + b*8192 (+512 lo)

  f32x4 hh0 = {0,0,0,0}, cr0 = {0,0,0,0}, hh1 = {0,0,0,0}, cr1 = {0,0,0,0};

  // ---- preamble: stage chunk 0 into buffer 0 ----
  if (xstage) {
    const float4 a = *(const float4*)xg;
    const float4 bq = *(const float4*)(xg + 4);
    half8 h, l;
#pragma unroll
    for (int m = 0; m < 4; ++m) {
      const float v = (&a.x)[m];
      const _Float16 hv = (_Float16)v;
      h[m] = hv; l[m] = (_Float16)((v - (float)hv) * 2048.0f);
    }
#pragma unroll
    for (int m = 0; m < 4; ++m) {
      const float v = (&bq.x)[m];
      const _Float16 hv = (_Float16)v;
      h[m + 4] = hv; l[m + 4] = (_Float16)((v - (float)hv) * 2048.0f);
    }
    *(half8*)&xs[sx_off] = h;
    *(half8*)&xs[2048 + sx_off] = l;
  }
  if (wstage) {
    const half8 h = *(const half8*)whg;
    const half8 l = *(const half8*)wlg;
    *(half8*)&xs[sw_off] = h;
    *(half8*)&xs[sw_off + 512] = l;
  }

  float4 pxa, pxb; half8 pwh, pwl;
  for (int c = 0; c < NCH; ++c) {
    __syncthreads();                      // buf (c&1) visible; buf (c&1)^1 free
    const int b  = c & 1;
    const int bn = b ^ 1;
    if (c + 1 < NCH) {                    // issue prefetch early (hide latency)
      if (xstage) {
        pxa = *(const float4*)(xg + (c + 1) * KC);
        pxb = *(const float4*)(xg + (c + 1) * KC + 4);
      }
      if (wstage) {
        pwh = *(const half8*)(whg + (size_t)(c + 1) * 512);
        pwl = *(const half8*)(wlg + (size_t)(c + 1) * 512);
      }
    }
    const half8 ah0 = *(const half8*)&xs[b * 4096 + offA0];
    const half8 al0 = *(const half8*)&xs[b * 4096 + 2048 + offA0];
    const half8 ah1 = *(const half8*)&xs[b * 4096 + offA1];
    const half8 al1 = *(const half8*)&xs[b * 4096 + 2048 + offA1];
    const half8 bh  = *(const half8*)&xs[b * 8192 + offB];
    const half8 bl  = *(const half8*)&xs[b * 8192 + offB + 512];

    hh0 = __builtin_amdgcn_mfma_f32_16x16x32_f16(ah0, bh, hh0, 0, 0, 0);
    cr0 = __builtin_amdgcn_mfma_f32_16x16x32_f16(ah0, bl, cr0, 0, 0, 0);
    cr0 = __builtin_amdgcn_mfma_f32_16x16x32_f16(al0, bh, cr0, 0, 0, 0);
    hh1 = __builtin_amdgcn_mfma_f32_16x16x32_f16(ah1, bh, hh1, 0, 0, 0);
    cr1 = __builtin_amdgcn_mfma_f32_16x16x32_f16(ah1, bl, cr1, 0, 0, 0);
    cr1 = __builtin_amdgcn_mfma_f32_16x16x32_f16(al1, bh, cr1, 0, 0, 0);

    if (c + 1 < NCH) {                    // convert + write into the free buffer
      if (xstage) {
        half8 h, l;
#pragma unroll
        for (int m = 0; m < 4; ++m) {
          const float v = (&pxa.x)[m];
          const _Float16 hv = (_Float16)v;
          h[m] = hv; l[m] = (_Float16)((v - (float)hv) * 2048.0f);
        }
#pragma unroll
        for (int m = 0; m < 4; ++m) {
          const float v = (&pxb.x)[m];
          const _Float16 hv = (_Float16)v;
          h[m + 4] = hv; l[m + 4] = (_Float16)((v - (float)hv) * 2048.0f);
        }
        *(half8*)&xs[bn * 4096 + sx_off] = h;
        *(half8*)&xs[bn * 4096 + 2048 + sx_off] = l;
      }
      if (wstage) {
        *(half8*)&xs[bn * 8192 + sw_off] = pwh;
        *(half8*)&xs[bn * 8192 + sw_off + 512] = pwl;
      }
    }
  }
  __syncthreads();                        // GEMM LDS dead

  // ---- unscale, add rnn, write emb to A (C/D: col=lane&15, row=quad*4+r) ----
  {
    const int e  = nt * 16 + col;
    const float rv = rnn[e];
#pragma unroll
    for (int r = 0; r < 4; ++r) {
      A[swz(mt0 * 16 + quad * 4 + r, e)] =
          hh0[r] * (1.0f / 32.0f) + cr0[r] * (1.0f / 65536.0f) + rv;
      A[swz(mt1 * 16 + quad * 4 + r, e)] =
          hh1[r] * (1.0f / 32.0f) + cr1[r] * (1.0f / 65536.0f) + rv;
    }
  }
  __syncthreads();

  // ---- LayerNorm + exact GELU: 4 tokens per wave; G -> G4 (float4-swizzled) ----
  const int e0 = wv * 8;                  // epilogue e-mapping
  {
    const float gm0 = gamma[lane], gm1 = gamma[lane + 64];
    const float bt0 = beta[lane],  bt1 = beta[lane + 64];
    for (int tt = wv * 4; tt < wv * 4 + 4; ++tt) {
      const float v0 = A[swz(tt, lane)];
      const float v1 = A[swz(tt, lane + 64)];
      float s = v0 + v1;
#pragma unroll
      for (int m = 32; m; m >>= 1) s += __shfl_xor(s, m);
      const float mu = s * (1.0f / 128.0f);
      const float d0 = v0 - mu, d1 = v1 - mu;
      float q = d0 * d0 + d1 * d1;
#pragma unroll
      for (int m = 32; m; m >>= 1) q += __shfl_xor(q, m);
      const float rstd = 1.0f / sqrtf(q * (1.0f / 128.0f) + 1e-5f);
      const float h0v = d0 * rstd * gm0 + bt0;
      const float h1v = d1 * rstd * gm1 + bt1;
      const float g0 = 0.5f * h0v * (1.0f + erff(h0v * 0.70710678118654752f));
      const float g1 = 0.5f * h1v * (1.0f + erff(h1v * 0.70710678118654752f));
      const int e0a = lane, e1a = lane + 64;
      G4[(tt * 32 + (((e0a >> 2) ^ (tt & 31)))) * 4 + (e0a & 3)] = g0;
      G4[(tt * 32 + (((e1a >> 2) ^ (tt & 31)))) * 4 + (e1a & 3)] = g1;
    }
  }
  __syncthreads();

  // ---- decoder GEMM: wave = 8 h-rows x 64 tokens (lane = token) ----
  {
    float acc2[8];
#pragma unroll
    for (int j = 0; j < 8; ++j) acc2[j] = 0.0f;
    const float4* wd4 = (const float4*)(Wd + (size_t)e0 * EDIM);  // uniform
#pragma unroll 2
    for (int kg = 0; kg < EDIM / 4; ++kg) {
      const float4 gv = *(const float4*)&G4[(lane * 32 + (kg ^ (lane & 31))) * 4];
#pragma unroll
      for (int j = 0; j < 8; ++j) {
        const float4 w = wd4[(size_t)j * (EDIM / 4) + kg];
        acc2[j] = fmaf(gv.x, w.x,
                  fmaf(gv.y, w.y,
                  fmaf(gv.z, w.z,
                  fmaf(gv.w, w.w, acc2[j]))));
      }
    }
    __syncthreads();
#pragma unroll
    for (int j = 0; j < 8; ++j) A[swz(lane, e0 + j)] = acc2[j];
  }
  __syncthreads();

  // ---- gumbel-sigmoid, exact top-k (value then lower-index), output ----
  for (int tt = wv * 4; tt < wv * 4 + 4; ++tt) {
    const size_t T = (size_t)(t0 + tt);
    const float l0 = A[swz(tt, lane)];
    const float l1 = A[swz(tt, lane + 64)];
    const float gn0 = gum[T * HDIM + lane];
    const float gn1 = gum[T * HDIM + lane + 64];
    const float z0 = (l0 + gn0 + 3.0f) * 2.5f;
    const float z1 = (l1 + gn1 + 3.0f) * 2.5f;
    const float ba0 = 1.0f / (1.0f + expf(-z0));
    const float ba1 = 1.0f / (1.0f + expf(-z1));
    const unsigned ub0 = __float_as_uint(ba0);   // ba in (0,1]: bits monotone
    const unsigned ub1 = __float_as_uint(ba1);
    const int r0 = ba0 > 0.5f;                   // round: 0.5 -> 0
    const int r1 = ba1 > 0.5f;
    const int cnt = __popcll(__ballot(r0)) + __popcll(__ballot(r1));
    float bin0, bin1;
    if (cnt > 32) {
      unsigned v = 0u;                            // radix-select 32nd largest
#pragma unroll
      for (int b = 29; b >= 0; --b) {
        const unsigned cand = v | (1u << b);
        const int cc = __popcll(__ballot(ub0 >= cand)) + __popcll(__ballot(ub1 >= cand));
        if (cc >= 32) v = cand;
      }
      const int cgt = __popcll(__ballot(ub0 > v)) + __popcll(__ballot(ub1 > v));
      const int r = 32 - cgt;                     // tied slots; lower index wins
      const unsigned long long t0b = __ballot(ub0 == v);
      const unsigned long long t1b = __ballot(ub1 == v);
      const int n0 = __popcll(t0b);
      const unsigned long long mlt = (1ull << lane) - 1ull;
      const int rk0 = __popcll(t0b & mlt);
      const int rk1 = n0 + __popcll(t1b & mlt);
      bin0 = (ub0 > v || (ub0 == v && rk0 < r)) ? 1.0f : 0.0f;
      bin1 = (ub1 > v || (ub1 == v && rk1 < r)) ? 1.0f : 0.0f;
    } else if (cnt == 0) {
      float m = fmaxf(ba0, ba1);
#pragma unroll
      for (int mm = 32; mm; mm >>= 1) m = fmaxf(m, __shfl_xor(m, mm));
      const unsigned long long e0b = __ballot(ba0 == m);
      const unsigned long long e1b = __ballot(ba1 == m);
      const int hstar = e0b ? (__ffsll((unsigned long long)e0b) - 1)
                            : (64 + __ffsll((unsigned long long)e1b) - 1);
      bin0 = (lane == hstar) ? 1.0f : 0.0f;
      bin1 = (lane + 64 == hstar) ? 1.0f : 0.0f;
    } else {
      bin0 = r0 ? 1.0f : 0.0f;
      bin1 = r1 ? 1.0f : 0.0f;
    }
    outb[T * HDIM + lane]      = bin0;
    outb[T * HDIM + lane + 64] = bin1;
    outa[T * HDIM + lane]      = ba0;
    outa[T * HDIM + lane + 64] = ba1;
  }
}

extern "C" void kernel_launch(void* const* d_in, const int* in_sizes, int n_in,
                              void* d_out, int out_size, void* d_ws, size_t ws_size,
                              hipStream_t stream) {
  (void)in_sizes; (void)n_in; (void)ws_size; (void)out_size;
  const float* x   = (const float*)d_in[0];
  const float* Wr  = (const float*)d_in[1];
  const float* Wd  = (const float*)d_in[2];
  const float* gm  = (const float*)d_in[3];
  const float* bt  = (const float*)d_in[4];
  const float* rnn = (const float*)d_in[5];
  const float* gum = (const float*)d_in[6];
  float* outb = (float*)d_out;
  float* outa = outb + (size_t)NTOK * HDIM;   // tuple: (binary, binary_approx)

  _Float16* wh = (_Float16*)d_ws;             // 512 KB
  _Float16* wl = wh + (size_t)EDIM * DDIM;    // 512 KB

  conv_w<<<dim3(128), dim3(256), 0, stream>>>(Wr, wh, wl);
  fused_router<<<dim3(NTOK / TOKT), dim3(1024), 0, stream>>>(
      x, wh, wl, Wd, gm, bt, rnn, gum, outb, outa);
}